// Round 3
// baseline (180.405 us; speedup 1.0000x reference)
//
#include <hip/hip_runtime.h>
#include <stdint.h>

typedef __bf16 bf16;
typedef __bf16 v8bf __attribute__((ext_vector_type(8)));
typedef float v4f __attribute__((ext_vector_type(4)));

#define T_SEQ   1024
#define D_MODEL 512
#define N_HEADS 8
#define D_HEAD  64
#define B_SZ    2
#define BH      (B_SZ * N_HEADS)     // 16
#define CHUNK   128
#define NCHUNK  (T_SEQ / CHUNK)      // 8
#define WN      (D_MODEL * D_MODEL)  // 262144

// ------------------------------------------------- weight quantize (3 stages)
struct AlphaArgs { const float* w[4]; float* partial; };

__global__ __launch_bounds__(256) void k_alpha(AlphaArgs a) {
    const int mid = blockIdx.y, blk = blockIdx.x, tid = threadIdx.x;
    const float* __restrict__ W = a.w[mid];
    float sabs = 0.f;
    #pragma unroll
    for (int k = 0; k < 4; ++k) {
        float4 v = ((const float4*)W)[blk * 1024 + k * 256 + tid];
        sabs += fabsf(v.x) + fabsf(v.y) + fabsf(v.z) + fabsf(v.w);
    }
    __shared__ float red[256];
    red[tid] = sabs;
    __syncthreads();
    for (int s = 128; s > 0; s >>= 1) {
        if (tid < s) red[tid] += red[tid + s];
        __syncthreads();
    }
    if (tid == 0) a.partial[mid * 64 + blk] = red[0];
}

__global__ __launch_bounds__(64) void k_scale(const float* __restrict__ partial,
                                              float* __restrict__ scales) {
    const int tid = threadIdx.x;
    if (tid < 4) {
        float s = 0.f;
        for (int i = 0; i < 64; ++i) s += partial[tid * 64 + i];
        float alpha = s / (float)WN + 1e-12f;
        float e = rintf(log2f(alpha));
        e = fminf(4.f, fmaxf(-4.f, e));
        scales[tid] = exp2f(e);
    }
}

struct WqArgs { const float* w[4]; bf16* wt[4]; const float* scales; };

__global__ __launch_bounds__(256) void k_wquant(WqArgs a) {
    const int mid = blockIdx.y, blk = blockIdx.x, tid = threadIdx.x;
    const float* __restrict__ W = a.w[mid];
    bf16* __restrict__ Wt = a.wt[mid];
    const float s = a.scales[mid];
    const float inv_s = 1.f / s;              // s is a power of two: exact
    #pragma unroll
    for (int k = 0; k < 4; ++k) {
        const int idx = blk * 1024 + k * 256 + tid;
        float4 v = ((const float4*)W)[idx];
        float vv[4] = {v.x, v.y, v.z, v.w};
        union { uint2 u; bf16 h[4]; } o;
        #pragma unroll
        for (int j = 0; j < 4; ++j) {
            float r = rintf(vv[j] * inv_s);
            r = fminf(1.f, fmaxf(-1.f, r));
            o.h[j] = (bf16)(r * s);
        }
        ((uint2*)Wt)[idx] = o.u;
    }
}

// ------------------------------------------------- x -> bf16 hi/lo split
__global__ __launch_bounds__(256) void k_xsplit(const float* __restrict__ x,
                                                bf16* __restrict__ xhi,
                                                bf16* __restrict__ xlo) {
    const int i = blockIdx.x * 256 + threadIdx.x;   // float4 index
    float4 v = ((const float4*)x)[i];
    float vv[4] = {v.x, v.y, v.z, v.w};
    union { uint2 u; bf16 h[4]; } H, L;
    #pragma unroll
    for (int j = 0; j < 4; ++j) {
        bf16 hb = (bf16)vv[j];
        H.h[j] = hb;
        L.h[j] = (bf16)(vv[j] - (float)hb);
    }
    ((uint2*)xhi)[i] = H.u;
    ((uint2*)xlo)[i] = L.u;
}

// ------------------------------------------------------------ GEMM cores
// C(64x64) = A[tm*64..][512] @ B[tn*64..][512]^T (NT). 16x16x32 bf16 MFMA.
// A-frag: A[m=lane&15][k=quad*8+j]; B-frag same from B rows. C/D: col=lane&15,
// row=quad*4+reg (m89-verified).
__device__ __forceinline__ void gemm_tile_64x64(
        const bf16* __restrict__ A, const bf16* __restrict__ Bm,
        int tm, int tn, bf16* As, bf16* Bs, v4f acc[4]) {
    const int tid = threadIdx.x;
    const int wid = tid >> 6, lane = tid & 63;
    const int q = lane >> 4, r = lane & 15;
    const int srow = tid >> 2;                // 0..63
    const int scol = (tid & 3) * 8;           // 0,8,16,24
    const bf16* Ag = A + ((size_t)(tm * 64 + srow)) * 512 + scol;
    const bf16* Bg = Bm + ((size_t)(tn * 64 + srow)) * 512 + scol;
    bf16* Asw = As + srow * 32 + scol;
    bf16* Bsw = Bs + srow * 32 + scol;
    for (int kk = 0; kk < 16; ++kk) {
        *(uint4*)Asw = *(const uint4*)(Ag + kk * 32);
        *(uint4*)Bsw = *(const uint4*)(Bg + kk * 32);
        __syncthreads();
        v8bf af = *(const v8bf*)(As + (wid * 16 + r) * 32 + q * 8);
        #pragma unroll
        for (int t = 0; t < 4; ++t) {
            v8bf bfr = *(const v8bf*)(Bs + (t * 16 + r) * 32 + q * 8);
            acc[t] = __builtin_amdgcn_mfma_f32_16x16x32_bf16(af, bfr, acc[t], 0, 0, 0);
        }
        __syncthreads();
    }
}

// dual-A (bf16x2 compensated) variant: C = (Ahi+Alo) @ B^T
__device__ __forceinline__ void gemm_tile_64x64_dual(
        const bf16* __restrict__ Ahi, const bf16* __restrict__ Alo,
        const bf16* __restrict__ Bm,
        int tm, int tn, bf16* As, bf16* As2, bf16* Bs, v4f acc[4]) {
    const int tid = threadIdx.x;
    const int wid = tid >> 6, lane = tid & 63;
    const int q = lane >> 4, r = lane & 15;
    const int srow = tid >> 2;
    const int scol = (tid & 3) * 8;
    const bf16* Ag  = Ahi + ((size_t)(tm * 64 + srow)) * 512 + scol;
    const bf16* Ag2 = Alo + ((size_t)(tm * 64 + srow)) * 512 + scol;
    const bf16* Bg  = Bm  + ((size_t)(tn * 64 + srow)) * 512 + scol;
    bf16* Asw  = As  + srow * 32 + scol;
    bf16* Asw2 = As2 + srow * 32 + scol;
    bf16* Bsw  = Bs  + srow * 32 + scol;
    for (int kk = 0; kk < 16; ++kk) {
        *(uint4*)Asw  = *(const uint4*)(Ag  + kk * 32);
        *(uint4*)Asw2 = *(const uint4*)(Ag2 + kk * 32);
        *(uint4*)Bsw  = *(const uint4*)(Bg  + kk * 32);
        __syncthreads();
        v8bf ah = *(const v8bf*)(As  + (wid * 16 + r) * 32 + q * 8);
        v8bf al = *(const v8bf*)(As2 + (wid * 16 + r) * 32 + q * 8);
        #pragma unroll
        for (int t = 0; t < 4; ++t) {
            v8bf bfr = *(const v8bf*)(Bs + (t * 16 + r) * 32 + q * 8);
            acc[t] = __builtin_amdgcn_mfma_f32_16x16x32_bf16(ah, bfr, acc[t], 0, 0, 0);
            acc[t] = __builtin_amdgcn_mfma_f32_16x16x32_bf16(al, bfr, acc[t], 0, 0, 0);
        }
        __syncthreads();
    }
}

// ------------------------------------------------- QKV projection (+phi)
struct QkvArgs {
    const bf16* xhi; const bf16* xlo;
    const bf16* wtq; const bf16* wtk; const bf16* wtv;
    const float* table;
    float* phiq; float* phik; float* vbuf;    // [16][1024][64] fp32
};

__global__ __launch_bounds__(256) void k_qkv(QkvArgs a) {
    __shared__ bf16 As[64 * 32] __attribute__((aligned(16)));
    __shared__ bf16 As2[64 * 32] __attribute__((aligned(16)));
    __shared__ bf16 Bs[64 * 32] __attribute__((aligned(16)));
    __shared__ float tab[512];
    const int tid = threadIdx.x;
    const int z = blockIdx.z;
    tab[tid] = a.table[tid];
    tab[tid + 256] = a.table[tid + 256];
    const bf16* Wm = (z == 0) ? a.wtq : ((z == 1) ? a.wtk : a.wtv);
    float* outb = (z == 0) ? a.phiq : ((z == 1) ? a.phik : a.vbuf);
    v4f acc[4];
    #pragma unroll
    for (int t = 0; t < 4; ++t) acc[t] = (v4f){0.f, 0.f, 0.f, 0.f};

    gemm_tile_64x64_dual(a.xhi, a.xlo, Wm, blockIdx.x, blockIdx.y, As, As2, Bs, acc);

    const int wid = tid >> 6, lane = tid & 63;
    const int q = lane >> 4, r = lane & 15;
    const int h = blockIdx.y;                 // tn*64 spans exactly head tn
    #pragma unroll
    for (int t = 0; t < 4; ++t) {
        const int d = t * 16 + r;
        #pragma unroll
        for (int i = 0; i < 4; ++i) {
            const int m = blockIdx.x * 64 + wid * 16 + q * 4 + i;
            const int b = m >> 10, tpos = m & 1023;
            const int bh = b * 8 + h;
            float val = acc[t][i];
            if (z < 2) {
                int i0 = (int)rintf(val / 0.1f) + 128;
                i0 = min(255, max(0, i0));
                int i1 = (int)rintf(val / 0.2f) + 128;
                i1 = min(255, max(0, i1));
                val = tab[i0] + tab[256 + i1];
            }
            outb[((size_t)bh * 1024 + tpos) * 64 + d] = val;
        }
    }
}

// ------------------------------------------------- per-chunk kv/k sums
__global__ __launch_bounds__(256) void k_chunksum(
        const float* __restrict__ phik, const float* __restrict__ vbuf,
        float* __restrict__ kvs, float* __restrict__ ks) {
    const int c = blockIdx.x, bh = blockIdx.y;
    __shared__ float pk[32][64] __attribute__((aligned(16)));
    __shared__ float vv[32][64] __attribute__((aligned(16)));
    const int tid = threadIdx.x;
    const int e = tid & 63, g = tid >> 6;
    float kv[16];
    #pragma unroll
    for (int i = 0; i < 16; ++i) kv[i] = 0.f;
    const int srow = tid >> 3, scol = (tid & 7) * 8;
    const size_t base = (size_t)bh * 1024 + c * 128;

    for (int sub = 0; sub < 4; ++sub) {
        __syncthreads();
        const float* pg = phik + (base + sub * 32 + srow) * 64 + scol;
        const float* vg = vbuf + (base + sub * 32 + srow) * 64 + scol;
        *(float4*)&pk[srow][scol]     = *(const float4*)pg;
        *(float4*)&pk[srow][scol + 4] = *(const float4*)(pg + 4);
        *(float4*)&vv[srow][scol]     = *(const float4*)vg;
        *(float4*)&vv[srow][scol + 4] = *(const float4*)(vg + 4);
        __syncthreads();
        for (int n = 0; n < 32; ++n) {
            const float vval = vv[n][e];
            const float4* prow = (const float4*)&pk[n][g * 16];
            float4 p0 = prow[0], p1 = prow[1], p2 = prow[2], p3 = prow[3];
            kv[0]  += p0.x * vval; kv[1]  += p0.y * vval; kv[2]  += p0.z * vval; kv[3]  += p0.w * vval;
            kv[4]  += p1.x * vval; kv[5]  += p1.y * vval; kv[6]  += p1.z * vval; kv[7]  += p1.w * vval;
            kv[8]  += p2.x * vval; kv[9]  += p2.y * vval; kv[10] += p2.z * vval; kv[11] += p2.w * vval;
            kv[12] += p3.x * vval; kv[13] += p3.y * vval; kv[14] += p3.z * vval; kv[15] += p3.w * vval;
        }
    }
    const size_t ob = ((size_t)bh * 8 + c) * 4096;
    #pragma unroll
    for (int i = 0; i < 16; ++i)
        kvs[ob + (g * 16 + i) * 64 + e] = kv[i];
    if (tid < 64) {
        float s = 0.f;
        for (int n = 0; n < 128; ++n) s += phik[(base + n) * 64 + tid];
        ks[((size_t)bh * 8 + c) * 64 + tid] = s;
    }
}

// ------------------------------------------------- exclusive chunk prefix
__global__ __launch_bounds__(256) void k_prefix(float* kvs, float* ks) {
    const int bh = blockIdx.x;
    const int tid = threadIdx.x;
    for (int p = tid; p < 4096; p += 256) {
        float run = 0.f;
        for (int c = 0; c < 8; ++c) {
            float* ptr = kvs + ((size_t)bh * 8 + c) * 4096 + p;
            float v = *ptr; *ptr = run; run += v;
        }
    }
    if (tid < 64) {
        float run = 0.f;
        for (int c = 0; c < 8; ++c) {
            float* ptr = ks + ((size_t)bh * 8 + c) * 64 + tid;
            float v = *ptr; *ptr = run; run += v;
        }
    }
}

// ------------------------------------------------- intra-chunk attention
__global__ __launch_bounds__(256) void k_attn(
        const float* __restrict__ phiq, const float* __restrict__ phik,
        const float* __restrict__ vbuf, const float* __restrict__ kvs,
        const float* __restrict__ ks, bf16* __restrict__ attn) {
    const int ntile = blockIdx.x, c = blockIdx.y, bh = blockIdx.z;
    __shared__ float pq[64][65];
    __shared__ float kv0[64][65];
    __shared__ float pkt[32][65];
    __shared__ float vt[32][65];
    __shared__ float Ss[64][33];
    __shared__ float kc0[64];
    __shared__ float Zs[64];
    const int tid = threadIdx.x;
    const int e = tid & 63, g = tid >> 6;
    const size_t tbase = (size_t)bh * 1024 + c * 128;
    const int t0 = ntile * 64;

    {   // stage phiQ rows and exclusive kv prefix
        const int row = tid >> 2, cb = (tid & 3) * 16;
        #pragma unroll
        for (int u = 0; u < 4; ++u) {
            float4 f = *(const float4*)(phiq + (tbase + t0 + row) * 64 + cb + 4 * u);
            pq[row][cb + 4 * u + 0] = f.x; pq[row][cb + 4 * u + 1] = f.y;
            pq[row][cb + 4 * u + 2] = f.z; pq[row][cb + 4 * u + 3] = f.w;
            float4 k = *(const float4*)(kvs + ((size_t)bh * 8 + c) * 4096 + row * 64 + cb + 4 * u);
            kv0[row][cb + 4 * u + 0] = k.x; kv0[row][cb + 4 * u + 1] = k.y;
            kv0[row][cb + 4 * u + 2] = k.z; kv0[row][cb + 4 * u + 3] = k.w;
        }
        if (tid < 64) kc0[tid] = ks[((size_t)bh * 8 + c) * 64 + tid];
    }
    __syncthreads();

    float out[16];
    #pragma unroll
    for (int j = 0; j < 16; ++j) {
        const int nl = g + 4 * j;
        float s = 0.f;
        #pragma unroll 8
        for (int d = 0; d < 64; ++d) s += pq[nl][d] * kv0[d][e];
        out[j] = s;
    }
    float zreg = 0.f;
    if (tid < 64) {
        #pragma unroll 8
        for (int d = 0; d < 64; ++d) zreg += pq[tid][d] * kc0[d];
    }

    const int ntiles_m = (ntile == 0) ? 2 : 4;
    for (int mt = 0; mt < ntiles_m; ++mt) {
        __syncthreads();
        {   // stage phiK/V m-tile
            const int row = tid >> 3, cb = (tid & 7) * 8;
            const float* pg = phik + (tbase + mt * 32 + row) * 64 + cb;
            const float* vg = vbuf + (tbase + mt * 32 + row) * 64 + cb;
            float4 f0 = *(const float4*)pg, f1 = *(const float4*)(pg + 4);
            pkt[row][cb + 0] = f0.x; pkt[row][cb + 1] = f0.y; pkt[row][cb + 2] = f0.z; pkt[row][cb + 3] = f0.w;
            pkt[row][cb + 4] = f1.x; pkt[row][cb + 5] = f1.y; pkt[row][cb + 6] = f1.z; pkt[row][cb + 7] = f1.w;
            float4 g0 = *(const float4*)vg, g1 = *(const float4*)(vg + 4);
            vt[row][cb + 0] = g0.x; vt[row][cb + 1] = g0.y; vt[row][cb + 2] = g0.z; vt[row][cb + 3] = g0.w;
            vt[row][cb + 4] = g1.x; vt[row][cb + 5] = g1.y; vt[row][cb + 6] = g1.z; vt[row][cb + 7] = g1.w;
        }
        __syncthreads();
        {   // S tile with causal mask
            const int nl = tid & 63, mb = (tid >> 6) * 8;
            const int nglob = t0 + nl;
            #pragma unroll
            for (int i = 0; i < 8; ++i) {
                const int ml = mb + i;
                float s = 0.f;
                #pragma unroll 8
                for (int d = 0; d < 64; ++d) s += pq[nl][d] * pkt[ml][d];
                Ss[nl][ml] = (mt * 32 + ml <= nglob) ? s : 0.f;
            }
        }
        __syncthreads();
        #pragma unroll
        for (int j = 0; j < 16; ++j) {
            const int nl = g + 4 * j;
            #pragma unroll 8
            for (int ml = 0; ml < 32; ++ml) out[j] += Ss[nl][ml] * vt[ml][e];
        }
        if (tid < 64) {
            #pragma unroll
            for (int ml = 0; ml < 32; ++ml) zreg += Ss[tid][ml];
        }
    }
    __syncthreads();
    if (tid < 64) Zs[tid] = fmaxf(zreg, 1e-6f);
    __syncthreads();

    const int b = bh >> 3, h = bh & 7;
    #pragma unroll
    for (int j = 0; j < 16; ++j) {
        const int nl = g + 4 * j;
        const float val = out[j] / Zs[nl];
        const size_t m = (size_t)b * 1024 + c * 128 + t0 + nl;
        attn[m * 512 + h * 64 + e] = (bf16)val;
    }
}

// ------------------------------------------------- output projection (f32 out)
struct OArgs { const bf16* attn; const bf16* wo; const float* bo; float* y; };

__global__ __launch_bounds__(256) void k_oproj(OArgs a) {
    __shared__ bf16 As[64 * 32] __attribute__((aligned(16)));
    __shared__ bf16 Bs[64 * 32] __attribute__((aligned(16)));
    v4f acc[4];
    #pragma unroll
    for (int t = 0; t < 4; ++t) acc[t] = (v4f){0.f, 0.f, 0.f, 0.f};
    gemm_tile_64x64(a.attn, a.wo, blockIdx.x, blockIdx.y, As, Bs, acc);
    const int tid = threadIdx.x;
    const int wid = tid >> 6, lane = tid & 63;
    const int q = lane >> 4, r = lane & 15;
    #pragma unroll
    for (int t = 0; t < 4; ++t) {
        const int n = blockIdx.y * 64 + t * 16 + r;
        const float bias = a.bo[n];
        #pragma unroll
        for (int i = 0; i < 4; ++i) {
            const int m = blockIdx.x * 64 + wid * 16 + q * 4 + i;
            a.y[(size_t)m * 512 + n] = acc[t][i] + bias;
        }
    }
}

// ---------------------------------------------------------------- launch
extern "C" void kernel_launch(void* const* d_in, const int* in_sizes, int n_in,
                              void* d_out, int out_size, void* d_ws, size_t ws_size,
                              hipStream_t stream) {
    const float* x   = (const float*)d_in[0];
    const float* Wq  = (const float*)d_in[1];
    const float* Wk  = (const float*)d_in[2];
    const float* Wv  = (const float*)d_in[3];
    const float* Wo  = (const float*)d_in[4];
    const float* bo  = (const float*)d_in[5];
    const float* tab = (const float*)d_in[6];

    uint8_t* w = (uint8_t*)d_ws;
    bf16* wt    = (bf16*)w;                                   // 4*262144 bf16 = 2 MB
    bf16* xhi   = wt + 4 * WN;                                // 1M bf16 = 2 MB
    bf16* xlo   = xhi + 1048576;                              // 2 MB
    float* phiq = (float*)(xlo + 1048576);                    // 1M f32 = 4 MB
    float* phik = phiq + (size_t)16 * 1024 * 64;
    float* vbuf = phik + (size_t)16 * 1024 * 64;
    float* kvs  = vbuf + (size_t)16 * 1024 * 64;              // 2 MB
    float* ks   = kvs + (size_t)16 * 8 * 4096;                // 32 KB
    bf16* attn  = (bf16*)(ks + 16 * 8 * 64);                  // 2 MB
    float* partial = (float*)(attn + (size_t)2048 * 512);     // 256 f32
    float* scales  = partial + 256;                           // 4 f32

    AlphaArgs aa;
    aa.w[0] = Wq; aa.w[1] = Wk; aa.w[2] = Wv; aa.w[3] = Wo;
    aa.partial = partial;
    k_alpha<<<dim3(64, 4), dim3(256), 0, stream>>>(aa);
    k_scale<<<dim3(1), dim3(64), 0, stream>>>(partial, scales);

    WqArgs qa;
    qa.w[0] = Wq; qa.w[1] = Wk; qa.w[2] = Wv; qa.w[3] = Wo;
    qa.wt[0] = wt; qa.wt[1] = wt + WN; qa.wt[2] = wt + 2 * WN; qa.wt[3] = wt + 3 * WN;
    qa.scales = scales;
    k_wquant<<<dim3(64, 4), dim3(256), 0, stream>>>(qa);

    k_xsplit<<<dim3(1024), dim3(256), 0, stream>>>(x, xhi, xlo);

    QkvArgs pa{ xhi, xlo, qa.wt[0], qa.wt[1], qa.wt[2], tab, phiq, phik, vbuf };
    k_qkv<<<dim3(32, 8, 3), dim3(256), 0, stream>>>(pa);

    k_chunksum<<<dim3(NCHUNK, BH), dim3(256), 0, stream>>>(phik, vbuf, kvs, ks);
    k_prefix<<<dim3(BH), dim3(256), 0, stream>>>(kvs, ks);
    k_attn<<<dim3(2, NCHUNK, BH), dim3(256), 0, stream>>>(phiq, phik, vbuf, kvs, ks, attn);

    OArgs oa{ attn, qa.wt[3], bo, (float*)d_out };
    k_oproj<<<dim3(32, 8), dim3(256), 0, stream>>>(oa);
}

// Round 4
// 137.533 us; speedup vs baseline: 1.3117x; 1.3117x over previous
//
#include <hip/hip_runtime.h>
#include <stdint.h>

typedef __bf16 bf16;
typedef __bf16 v8bf __attribute__((ext_vector_type(8)));
typedef float v4f __attribute__((ext_vector_type(4)));

#define T_SEQ   1024
#define D_MODEL 512
#define N_HEADS 8
#define D_HEAD  64
#define B_SZ    2
#define BH      (B_SZ * N_HEADS)     // 16
#define CHUNK   128
#define NCHUNK  (T_SEQ / CHUNK)      // 8
#define WN      (D_MODEL * D_MODEL)  // 262144

// ------------------------------------------------- weight quantize (3 stages)
struct AlphaArgs { const float* w[4]; float* partial; };

__global__ __launch_bounds__(256) void k_alpha(AlphaArgs a) {
    const int mid = blockIdx.y, blk = blockIdx.x, tid = threadIdx.x;
    const float* __restrict__ W = a.w[mid];
    float sabs = 0.f;
    #pragma unroll
    for (int k = 0; k < 4; ++k) {
        float4 v = ((const float4*)W)[blk * 1024 + k * 256 + tid];
        sabs += fabsf(v.x) + fabsf(v.y) + fabsf(v.z) + fabsf(v.w);
    }
    __shared__ float red[256];
    red[tid] = sabs;
    __syncthreads();
    for (int s = 128; s > 0; s >>= 1) {
        if (tid < s) red[tid] += red[tid + s];
        __syncthreads();
    }
    if (tid == 0) a.partial[mid * 64 + blk] = red[0];
}

__global__ __launch_bounds__(64) void k_scale(const float* __restrict__ partial,
                                              float* __restrict__ scales) {
    const int tid = threadIdx.x;
    if (tid < 4) {
        float s = 0.f;
        for (int i = 0; i < 64; ++i) s += partial[tid * 64 + i];
        float alpha = s / (float)WN + 1e-12f;
        float e = rintf(log2f(alpha));
        e = fminf(4.f, fmaxf(-4.f, e));
        scales[tid] = exp2f(e);
    }
}

struct WqArgs { const float* w[4]; bf16* wt[4]; const float* scales; };

__global__ __launch_bounds__(256) void k_wquant(WqArgs a) {
    const int mid = blockIdx.y, blk = blockIdx.x, tid = threadIdx.x;
    const float* __restrict__ W = a.w[mid];
    bf16* __restrict__ Wt = a.wt[mid];
    const float s = a.scales[mid];
    const float inv_s = 1.f / s;              // s is a power of two: exact
    #pragma unroll
    for (int k = 0; k < 4; ++k) {
        const int idx = blk * 1024 + k * 256 + tid;
        float4 v = ((const float4*)W)[idx];
        float vv[4] = {v.x, v.y, v.z, v.w};
        union { uint2 u; bf16 h[4]; } o;
        #pragma unroll
        for (int j = 0; j < 4; ++j) {
            float r = rintf(vv[j] * inv_s);
            r = fminf(1.f, fmaxf(-1.f, r));
            o.h[j] = (bf16)(r * s);
        }
        ((uint2*)Wt)[idx] = o.u;
    }
}

// ------------------------------------------------- x -> bf16 hi/lo split
__global__ __launch_bounds__(256) void k_xsplit(const float* __restrict__ x,
                                                bf16* __restrict__ xhi,
                                                bf16* __restrict__ xlo) {
    const int i = blockIdx.x * 256 + threadIdx.x;   // float4 index
    float4 v = ((const float4*)x)[i];
    float vv[4] = {v.x, v.y, v.z, v.w};
    union { uint2 u; bf16 h[4]; } H, L;
    #pragma unroll
    for (int j = 0; j < 4; ++j) {
        bf16 hb = (bf16)vv[j];
        H.h[j] = hb;
        L.h[j] = (bf16)(vv[j] - (float)hb);
    }
    ((uint2*)xhi)[i] = H.u;
    ((uint2*)xlo)[i] = L.u;
}

// ------------------------------------------------------------ GEMM cores
// C(64x64) = A[tm*64..][512] @ B[tn*64..][512]^T (NT). 16x16x32 bf16 MFMA.
// A-frag: A[m=lane&15][k=quad*8+j]; B-frag same from B rows. C/D: col=lane&15,
// row=quad*4+reg (m89-verified).
__device__ __forceinline__ void gemm_tile_64x64(
        const bf16* __restrict__ A, const bf16* __restrict__ Bm,
        int tm, int tn, bf16* As, bf16* Bs, v4f acc[4]) {
    const int tid = threadIdx.x;
    const int wid = tid >> 6, lane = tid & 63;
    const int q = lane >> 4, r = lane & 15;
    const int srow = tid >> 2;                // 0..63
    const int scol = (tid & 3) * 8;           // 0,8,16,24
    const bf16* Ag = A + ((size_t)(tm * 64 + srow)) * 512 + scol;
    const bf16* Bg = Bm + ((size_t)(tn * 64 + srow)) * 512 + scol;
    bf16* Asw = As + srow * 32 + scol;
    bf16* Bsw = Bs + srow * 32 + scol;
    for (int kk = 0; kk < 16; ++kk) {
        *(uint4*)Asw = *(const uint4*)(Ag + kk * 32);
        *(uint4*)Bsw = *(const uint4*)(Bg + kk * 32);
        __syncthreads();
        v8bf af = *(const v8bf*)(As + (wid * 16 + r) * 32 + q * 8);
        #pragma unroll
        for (int t = 0; t < 4; ++t) {
            v8bf bfr = *(const v8bf*)(Bs + (t * 16 + r) * 32 + q * 8);
            acc[t] = __builtin_amdgcn_mfma_f32_16x16x32_bf16(af, bfr, acc[t], 0, 0, 0);
        }
        __syncthreads();
    }
}

// dual-A (bf16x2 compensated) variant: C = (Ahi+Alo) @ B^T
__device__ __forceinline__ void gemm_tile_64x64_dual(
        const bf16* __restrict__ Ahi, const bf16* __restrict__ Alo,
        const bf16* __restrict__ Bm,
        int tm, int tn, bf16* As, bf16* As2, bf16* Bs, v4f acc[4]) {
    const int tid = threadIdx.x;
    const int wid = tid >> 6, lane = tid & 63;
    const int q = lane >> 4, r = lane & 15;
    const int srow = tid >> 2;
    const int scol = (tid & 3) * 8;
    const bf16* Ag  = Ahi + ((size_t)(tm * 64 + srow)) * 512 + scol;
    const bf16* Ag2 = Alo + ((size_t)(tm * 64 + srow)) * 512 + scol;
    const bf16* Bg  = Bm  + ((size_t)(tn * 64 + srow)) * 512 + scol;
    bf16* Asw  = As  + srow * 32 + scol;
    bf16* Asw2 = As2 + srow * 32 + scol;
    bf16* Bsw  = Bs  + srow * 32 + scol;
    for (int kk = 0; kk < 16; ++kk) {
        *(uint4*)Asw  = *(const uint4*)(Ag  + kk * 32);
        *(uint4*)Asw2 = *(const uint4*)(Ag2 + kk * 32);
        *(uint4*)Bsw  = *(const uint4*)(Bg  + kk * 32);
        __syncthreads();
        v8bf ah = *(const v8bf*)(As  + (wid * 16 + r) * 32 + q * 8);
        v8bf al = *(const v8bf*)(As2 + (wid * 16 + r) * 32 + q * 8);
        #pragma unroll
        for (int t = 0; t < 4; ++t) {
            v8bf bfr = *(const v8bf*)(Bs + (t * 16 + r) * 32 + q * 8);
            acc[t] = __builtin_amdgcn_mfma_f32_16x16x32_bf16(ah, bfr, acc[t], 0, 0, 0);
            acc[t] = __builtin_amdgcn_mfma_f32_16x16x32_bf16(al, bfr, acc[t], 0, 0, 0);
        }
        __syncthreads();
    }
}

// ------------------------------------------------- QKV projection (+phi)
// Outputs: z=0 phiQ bf16 natural [bh][t][d]
//          z=1 phiK bf16 natural + phiK f32 natural
//          z=2 V    f32 natural + V^T bf16 [bh][e][t]
struct QkvArgs {
    const bf16* xhi; const bf16* xlo;
    const bf16* wtq; const bf16* wtk; const bf16* wtv;
    const float* table;
    bf16* phiqB; bf16* phikB; float* phikF;
    float* vbufF; bf16* vbufT;
};

__global__ __launch_bounds__(256) void k_qkv(QkvArgs a) {
    __shared__ bf16 As[64 * 32] __attribute__((aligned(16)));
    __shared__ bf16 As2[64 * 32] __attribute__((aligned(16)));
    __shared__ bf16 Bs[64 * 32] __attribute__((aligned(16)));
    __shared__ float tab[512];
    const int tid = threadIdx.x;
    const int z = blockIdx.z;
    tab[tid] = a.table[tid];
    tab[tid + 256] = a.table[tid + 256];
    const bf16* Wm = (z == 0) ? a.wtq : ((z == 1) ? a.wtk : a.wtv);
    v4f acc[4];
    #pragma unroll
    for (int t = 0; t < 4; ++t) acc[t] = (v4f){0.f, 0.f, 0.f, 0.f};

    gemm_tile_64x64_dual(a.xhi, a.xlo, Wm, blockIdx.x, blockIdx.y, As, As2, Bs, acc);

    const int wid = tid >> 6, lane = tid & 63;
    const int q = lane >> 4, r = lane & 15;
    const int h = blockIdx.y;                 // tn*64 spans exactly head tn
    const int mbase = blockIdx.x * 64 + wid * 16 + q * 4;
    const int b = mbase >> 10, tposb = mbase & 1023;
    const int bh = b * 8 + h;
    #pragma unroll
    for (int t = 0; t < 4; ++t) {
        const int d = t * 16 + r;
        float vals[4];
        #pragma unroll
        for (int i = 0; i < 4; ++i) {
            float val = acc[t][i];
            if (z < 2) {
                int i0 = (int)rintf(val / 0.1f) + 128;
                i0 = min(255, max(0, i0));
                int i1 = (int)rintf(val / 0.2f) + 128;
                i1 = min(255, max(0, i1));
                val = tab[i0] + tab[256 + i1];
            }
            vals[i] = val;
            const size_t idx = ((size_t)bh * 1024 + tposb + i) * 64 + d;
            if (z == 0) {
                a.phiqB[idx] = (bf16)val;
            } else if (z == 1) {
                a.phikB[idx] = (bf16)val;
                a.phikF[idx] = val;
            } else {
                a.vbufF[idx] = val;
            }
        }
        if (z == 2) {
            union { uint2 u; bf16 h4[4]; } P;
            #pragma unroll
            for (int i = 0; i < 4; ++i) P.h4[i] = (bf16)vals[i];
            *(uint2*)&a.vbufT[((size_t)bh * 64 + d) * 1024 + tposb] = P.u;
        }
    }
}

// ------------------------------------------------- per-chunk kv/k sums
// kvT output TRANSPOSED: kvT[bh][c][e*64+d]
__global__ __launch_bounds__(256) void k_chunksum(
        const float* __restrict__ phikF, const float* __restrict__ vbufF,
        float* __restrict__ kvT, float* __restrict__ ks) {
    const int c = blockIdx.x, bh = blockIdx.y;
    __shared__ float pk[32][64] __attribute__((aligned(16)));
    __shared__ float vv[32][64] __attribute__((aligned(16)));
    const int tid = threadIdx.x;
    const int e = tid & 63, g = tid >> 6;
    float kv[16];
    #pragma unroll
    for (int i = 0; i < 16; ++i) kv[i] = 0.f;
    const int srow = tid >> 3, scol = (tid & 7) * 8;
    const size_t base = (size_t)bh * 1024 + c * 128;

    for (int sub = 0; sub < 4; ++sub) {
        __syncthreads();
        const float* pg = phikF + (base + sub * 32 + srow) * 64 + scol;
        const float* vg = vbufF + (base + sub * 32 + srow) * 64 + scol;
        *(float4*)&pk[srow][scol]     = *(const float4*)pg;
        *(float4*)&pk[srow][scol + 4] = *(const float4*)(pg + 4);
        *(float4*)&vv[srow][scol]     = *(const float4*)vg;
        *(float4*)&vv[srow][scol + 4] = *(const float4*)(vg + 4);
        __syncthreads();
        for (int n = 0; n < 32; ++n) {
            const float vval = vv[n][e];
            const float4* prow = (const float4*)&pk[n][g * 16];
            float4 p0 = prow[0], p1 = prow[1], p2 = prow[2], p3 = prow[3];
            kv[0]  += p0.x * vval; kv[1]  += p0.y * vval; kv[2]  += p0.z * vval; kv[3]  += p0.w * vval;
            kv[4]  += p1.x * vval; kv[5]  += p1.y * vval; kv[6]  += p1.z * vval; kv[7]  += p1.w * vval;
            kv[8]  += p2.x * vval; kv[9]  += p2.y * vval; kv[10] += p2.z * vval; kv[11] += p2.w * vval;
            kv[12] += p3.x * vval; kv[13] += p3.y * vval; kv[14] += p3.z * vval; kv[15] += p3.w * vval;
        }
    }
    const size_t ob = ((size_t)bh * 8 + c) * 4096;
    #pragma unroll
    for (int w = 0; w < 4; ++w) {
        float4 s4 = {kv[4 * w], kv[4 * w + 1], kv[4 * w + 2], kv[4 * w + 3]};
        *(float4*)&kvT[ob + e * 64 + g * 16 + 4 * w] = s4;   // transposed [e][d]
    }
    if (tid < 64) {
        float s = 0.f;
        for (int n = 0; n < 128; ++n) s += phikF[(base + n) * 64 + tid];
        ks[((size_t)bh * 8 + c) * 64 + tid] = s;
    }
}

// ------------------------------------------------- exclusive chunk prefix
// writes bf16 exclusive prefix kvsB; ks prefixed in place (f32)
__global__ __launch_bounds__(256) void k_prefix(const float* __restrict__ kvT,
                                                bf16* __restrict__ kvsB,
                                                float* __restrict__ ks) {
    const int bh = blockIdx.x;
    const int tid = threadIdx.x;
    for (int p = tid; p < 4096; p += 256) {
        float run = 0.f;
        for (int c = 0; c < 8; ++c) {
            const size_t off = ((size_t)bh * 8 + c) * 4096 + p;
            kvsB[off] = (bf16)run;
            run += kvT[off];
        }
    }
    if (tid < 64) {
        float run = 0.f;
        for (int c = 0; c < 8; ++c) {
            float* ptr = ks + ((size_t)bh * 8 + c) * 64 + tid;
            float v = *ptr; *ptr = run; run += v;
        }
    }
}

// ------------------------------------------------- intra-chunk attention (MFMA)
// Per block: 64 Q-rows (ntile of chunk c, head bh).
//   out  = phiQ @ kv0           (kv0 = exclusive chunk prefix, bf16, [e][d])
//   S    = phiQ @ phiK^T        (masked causal within chunk)
//   out += P @ V                (P = masked S via LDS bf16; V^T rows [e][m])
//   Z    = rowsum(P) + phiQ . kc0
__global__ __launch_bounds__(256) void k_attn(
        const bf16* __restrict__ phiqB, const bf16* __restrict__ phikB,
        const bf16* __restrict__ vbufT, const bf16* __restrict__ kvsB,
        const float* __restrict__ ks, bf16* __restrict__ attn) {
    const int ntile = blockIdx.x, c = blockIdx.y, bh = blockIdx.z;
    // LDS pool, Pbs overlays pqs+kv0s (they are dead once phase A + Z0 done)
    __shared__ char smem[56064] __attribute__((aligned(16)));
    bf16* pqs  = (bf16*)smem;               // [64][72]
    bf16* kv0s = (bf16*)(smem + 9216);      // [64][72]
    bf16* Pbs  = (bf16*)smem;               // [64][136] overlay
    bf16* pks  = (bf16*)(smem + 18432);     // [128][72]
    bf16* vts  = (bf16*)(smem + 36864);     // [64][136]
    float* kc0s = (float*)(smem + 54272);   // [64]
    float* Zrow = (float*)(smem + 54528);   // [64]
    float* Zp   = (float*)(smem + 54784);   // [4][64]
    float* Zs   = (float*)(smem + 55808);   // [64]

    const int tid = threadIdx.x;
    const int wid = tid >> 6, lane = tid & 63;
    const int q = lane >> 4, r = lane & 15;
    const size_t tbase = (size_t)bh * 1024 + c * 128;
    const int t0 = ntile * 64;

    // ---- stage (all operands already bf16 in global)
    #pragma unroll
    for (int k = 0; k < 2; ++k) {
        const int idx = k * 256 + tid;
        const int row = idx >> 3, col = (idx & 7) * 8;
        *(uint4*)&pqs[row * 72 + col] =
            *(const uint4*)&phiqB[(tbase + t0 + row) * 64 + col];
        *(uint4*)&kv0s[row * 72 + col] =
            *(const uint4*)&kvsB[(((size_t)bh * 8 + c) * 64 + row) * 64 + col];
    }
    #pragma unroll
    for (int k = 0; k < 4; ++k) {
        const int idx = k * 256 + tid;
        const int row = idx >> 3, col = (idx & 7) * 8;
        *(uint4*)&pks[row * 72 + col] =
            *(const uint4*)&phikB[(tbase + row) * 64 + col];
        const int row2 = idx >> 4, col2 = (idx & 15) * 8;
        *(uint4*)&vts[row2 * 136 + col2] =
            *(const uint4*)&vbufT[((size_t)bh * 64 + row2) * 1024 + c * 128 + col2];
    }
    if (tid < 64) kc0s[tid] = ks[((size_t)bh * 8 + c) * 64 + tid];
    __syncthreads();

    // ---- phase A: out1 + S MFMAs, Z0 partials
    v4f oacc[4], sacc[8];
    #pragma unroll
    for (int t = 0; t < 4; ++t) oacc[t] = (v4f){0.f, 0.f, 0.f, 0.f};
    #pragma unroll
    for (int u = 0; u < 8; ++u) sacc[u] = (v4f){0.f, 0.f, 0.f, 0.f};
    const int nmt = (ntile == 0) ? 4 : 8;     // active m-tiles (m<=n mask)

    #pragma unroll
    for (int kk = 0; kk < 2; ++kk) {
        v8bf af = *(const v8bf*)&pqs[(wid * 16 + r) * 72 + kk * 32 + q * 8];
        #pragma unroll
        for (int t = 0; t < 4; ++t) {
            v8bf bfr = *(const v8bf*)&kv0s[(t * 16 + r) * 72 + kk * 32 + q * 8];
            oacc[t] = __builtin_amdgcn_mfma_f32_16x16x32_bf16(af, bfr, oacc[t], 0, 0, 0);
        }
        #pragma unroll
        for (int u = 0; u < 8; ++u) {
            if (u < nmt) {
                v8bf bk = *(const v8bf*)&pks[(u * 16 + r) * 72 + kk * 32 + q * 8];
                sacc[u] = __builtin_amdgcn_mfma_f32_16x16x32_bf16(af, bk, sacc[u], 0, 0, 0);
            }
        }
    }
    {   // Z0 partial: wave wid covers d = wid*16..wid*16+15, all 64 rows
        float z0 = 0.f;
        #pragma unroll
        for (int j = 0; j < 16; ++j)
            z0 += (float)pqs[lane * 72 + wid * 16 + j] * kc0s[wid * 16 + j];
        Zp[wid * 64 + lane] = z0;
    }
    __syncthreads();   // pqs/kv0s dead; Pbs overlay may now be written

    // ---- mask, rowsum, write P (bf16, A-layout rows)
    float zi[4] = {0.f, 0.f, 0.f, 0.f};
    #pragma unroll
    for (int u = 0; u < 8; ++u) {
        if (u < nmt) {
            const int m = u * 16 + r;
            #pragma unroll
            for (int i = 0; i < 4; ++i) {
                const int nloc = t0 + wid * 16 + q * 4 + i;
                const float sv = (m <= nloc) ? sacc[u][i] : 0.f;
                zi[i] += sv;
                Pbs[(wid * 16 + q * 4 + i) * 136 + m] = (bf16)sv;
            }
        }
    }
    #pragma unroll
    for (int w = 1; w < 16; w <<= 1) {
        #pragma unroll
        for (int i = 0; i < 4; ++i) zi[i] += __shfl_xor(zi[i], w);
    }
    if (r == 0) {
        #pragma unroll
        for (int i = 0; i < 4; ++i) Zrow[wid * 16 + q * 4 + i] = zi[i];
    }
    __syncthreads();

    if (tid < 64)
        Zs[tid] = fmaxf(Zrow[tid] + Zp[tid] + Zp[64 + tid] + Zp[128 + tid] + Zp[192 + tid],
                        1e-6f);
    __syncthreads();

    // ---- phase B: out += P @ V
    const int nkk = (ntile == 0) ? 2 : 4;
    #pragma unroll
    for (int kk = 0; kk < 4; ++kk) {
        if (kk < nkk) {
            v8bf af = *(const v8bf*)&Pbs[(wid * 16 + r) * 136 + kk * 32 + q * 8];
            #pragma unroll
            for (int t = 0; t < 4; ++t) {
                v8bf bfr = *(const v8bf*)&vts[(t * 16 + r) * 136 + kk * 32 + q * 8];
                oacc[t] = __builtin_amdgcn_mfma_f32_16x16x32_bf16(af, bfr, oacc[t], 0, 0, 0);
            }
        }
    }

    // ---- epilogue
    const int b = bh >> 3, h = bh & 7;
    #pragma unroll
    for (int t = 0; t < 4; ++t) {
        const int e = t * 16 + r;
        #pragma unroll
        for (int i = 0; i < 4; ++i) {
            const int row = wid * 16 + q * 4 + i;
            const float val = oacc[t][i] / Zs[row];
            const size_t mtok = (size_t)b * 1024 + c * 128 + t0 + row;
            attn[mtok * 512 + h * 64 + e] = (bf16)val;
        }
    }
}

// ------------------------------------------------- output projection (f32 out)
struct OArgs { const bf16* attn; const bf16* wo; const float* bo; float* y; };

__global__ __launch_bounds__(256) void k_oproj(OArgs a) {
    __shared__ bf16 As[64 * 32] __attribute__((aligned(16)));
    __shared__ bf16 Bs[64 * 32] __attribute__((aligned(16)));
    v4f acc[4];
    #pragma unroll
    for (int t = 0; t < 4; ++t) acc[t] = (v4f){0.f, 0.f, 0.f, 0.f};
    gemm_tile_64x64(a.attn, a.wo, blockIdx.x, blockIdx.y, As, Bs, acc);
    const int tid = threadIdx.x;
    const int wid = tid >> 6, lane = tid & 63;
    const int q = lane >> 4, r = lane & 15;
    #pragma unroll
    for (int t = 0; t < 4; ++t) {
        const int n = blockIdx.y * 64 + t * 16 + r;
        const float bias = a.bo[n];
        #pragma unroll
        for (int i = 0; i < 4; ++i) {
            const int m = blockIdx.x * 64 + wid * 16 + q * 4 + i;
            a.y[(size_t)m * 512 + n] = acc[t][i] + bias;
        }
    }
}

// ---------------------------------------------------------------- launch
extern "C" void kernel_launch(void* const* d_in, const int* in_sizes, int n_in,
                              void* d_out, int out_size, void* d_ws, size_t ws_size,
                              hipStream_t stream) {
    const float* x   = (const float*)d_in[0];
    const float* Wq  = (const float*)d_in[1];
    const float* Wk  = (const float*)d_in[2];
    const float* Wv  = (const float*)d_in[3];
    const float* Wo  = (const float*)d_in[4];
    const float* bo  = (const float*)d_in[5];
    const float* tab = (const float*)d_in[6];

    uint8_t* w = (uint8_t*)d_ws;
    bf16* wt     = (bf16*)w;                                  // 2 MB
    bf16* xhi    = wt + 4 * WN;                               // 2 MB
    bf16* xlo    = xhi + 1048576;                             // 2 MB
    float* phikF = (float*)(xlo + 1048576);                   // 4 MB
    float* vbufF = phikF + (size_t)16 * 1024 * 64;            // 4 MB
    float* kvT   = vbufF + (size_t)16 * 1024 * 64;            // 2 MB
    float* ks    = kvT + (size_t)16 * 8 * 4096;               // 32 KB
    bf16* attn   = (bf16*)(ks + 16 * 8 * 64);                 // 2 MB
    bf16* phiqB  = attn + (size_t)2048 * 512;                 // 2 MB
    bf16* phikB  = phiqB + (size_t)16 * 1024 * 64;            // 2 MB
    bf16* vbufT  = phikB + (size_t)16 * 1024 * 64;            // 2 MB
    bf16* kvsB   = vbufT + (size_t)16 * 64 * 1024;            // 1 MB
    float* partial = (float*)(kvsB + (size_t)16 * 8 * 4096);  // 256 f32
    float* scales  = partial + 256;                           // 4 f32

    AlphaArgs aa;
    aa.w[0] = Wq; aa.w[1] = Wk; aa.w[2] = Wv; aa.w[3] = Wo;
    aa.partial = partial;
    k_alpha<<<dim3(64, 4), dim3(256), 0, stream>>>(aa);
    k_scale<<<dim3(1), dim3(64), 0, stream>>>(partial, scales);

    WqArgs qa;
    qa.w[0] = Wq; qa.w[1] = Wk; qa.w[2] = Wv; qa.w[3] = Wo;
    qa.wt[0] = wt; qa.wt[1] = wt + WN; qa.wt[2] = wt + 2 * WN; qa.wt[3] = wt + 3 * WN;
    qa.scales = scales;
    k_wquant<<<dim3(64, 4), dim3(256), 0, stream>>>(qa);

    k_xsplit<<<dim3(1024), dim3(256), 0, stream>>>(x, xhi, xlo);

    QkvArgs pa{ xhi, xlo, qa.wt[0], qa.wt[1], qa.wt[2], tab,
                phiqB, phikB, phikF, vbufF, vbufT };
    k_qkv<<<dim3(32, 8, 3), dim3(256), 0, stream>>>(pa);

    k_chunksum<<<dim3(NCHUNK, BH), dim3(256), 0, stream>>>(phikF, vbufF, kvT, ks);
    k_prefix<<<dim3(BH), dim3(256), 0, stream>>>(kvT, kvsB, ks);
    k_attn<<<dim3(2, NCHUNK, BH), dim3(256), 0, stream>>>(phiqB, phikB, vbufT, kvsB, ks, attn);

    OArgs oa{ attn, qa.wt[3], bo, (float*)d_out };
    k_oproj<<<dim3(32, 8), dim3(256), 0, stream>>>(oa);
}

// Round 5
// 131.610 us; speedup vs baseline: 1.3708x; 1.0450x over previous
//
#include <hip/hip_runtime.h>
#include <stdint.h>

typedef __bf16 bf16;
typedef __bf16 v8bf __attribute__((ext_vector_type(8)));
typedef float v4f __attribute__((ext_vector_type(4)));

#define T_SEQ   1024
#define D_MODEL 512
#define N_HEADS 8
#define D_HEAD  64
#define B_SZ    2
#define BH      (B_SZ * N_HEADS)     // 16
#define CHUNK   128
#define NCHUNK  (T_SEQ / CHUNK)      // 8
#define WN      (D_MODEL * D_MODEL)  // 262144

// async global->LDS, 16B per lane; lds dest must be wave-uniform base (+lane*16)
__device__ __forceinline__ void lds16(const void* g, void* l) {
    __builtin_amdgcn_global_load_lds(
        (const __attribute__((address_space(1))) uint32_t*)g,
        (__attribute__((address_space(3))) uint32_t*)l, 16, 0, 0);
}

// ------------------------------------------------- weight quantize (2 stages)
struct AlphaArgs { const float* w[4]; float* partial; };

__global__ __launch_bounds__(256) void k_alpha(AlphaArgs a) {
    const int mid = blockIdx.y, blk = blockIdx.x, tid = threadIdx.x;
    const float* __restrict__ W = a.w[mid];
    float sabs = 0.f;
    #pragma unroll
    for (int k = 0; k < 4; ++k) {
        float4 v = ((const float4*)W)[blk * 1024 + k * 256 + tid];
        sabs += fabsf(v.x) + fabsf(v.y) + fabsf(v.z) + fabsf(v.w);
    }
    __shared__ float red[256];
    red[tid] = sabs;
    __syncthreads();
    for (int s = 128; s > 0; s >>= 1) {
        if (tid < s) red[tid] += red[tid + s];
        __syncthreads();
    }
    if (tid == 0) a.partial[mid * 64 + blk] = red[0];
}

struct WqArgs { const float* w[4]; bf16* wt[4]; const float* partial; };

__global__ __launch_bounds__(256) void k_wquant(WqArgs a) {
    const int mid = blockIdx.y, blk = blockIdx.x, tid = threadIdx.x;
    const float* __restrict__ W = a.w[mid];
    bf16* __restrict__ Wt = a.wt[mid];
    __shared__ float sv;
    if (tid < 64) {
        float p = a.partial[mid * 64 + tid];
        #pragma unroll
        for (int w = 1; w < 64; w <<= 1) p += __shfl_xor(p, w);
        if (tid == 0) {
            float alpha = p / (float)WN + 1e-12f;
            float e = rintf(log2f(alpha));
            e = fminf(4.f, fmaxf(-4.f, e));
            sv = exp2f(e);
        }
    }
    __syncthreads();
    const float s = sv;
    const float inv_s = 1.f / s;              // s is a power of two: exact
    #pragma unroll
    for (int k = 0; k < 4; ++k) {
        const int idx = blk * 1024 + k * 256 + tid;
        float4 v = ((const float4*)W)[idx];
        float vv[4] = {v.x, v.y, v.z, v.w};
        union { uint2 u; bf16 h[4]; } o;
        #pragma unroll
        for (int j = 0; j < 4; ++j) {
            float r = rintf(vv[j] * inv_s);
            r = fminf(1.f, fmaxf(-1.f, r));
            o.h[j] = (bf16)(r * s);
        }
        ((uint2*)Wt)[idx] = o.u;
    }
}

// ------------------------------------------------- x -> bf16 hi/lo split
__global__ __launch_bounds__(256) void k_xsplit(const float* __restrict__ x,
                                                bf16* __restrict__ xhi,
                                                bf16* __restrict__ xlo) {
    const int i = blockIdx.x * 256 + threadIdx.x;   // float4 index
    float4 v = ((const float4*)x)[i];
    float vv[4] = {v.x, v.y, v.z, v.w};
    union { uint2 u; bf16 h[4]; } H, L;
    #pragma unroll
    for (int j = 0; j < 4; ++j) {
        bf16 hb = (bf16)vv[j];
        H.h[j] = hb;
        L.h[j] = (bf16)(vv[j] - (float)hb);
    }
    ((uint2*)xhi)[i] = H.u;
    ((uint2*)xlo)[i] = L.u;
}

// ------------------------------------------------- fused QKV GEMM (+phi)
// C slab (128x128) = x[tm*128..][512] @ Wstk[tn*128..][512]^T (NT).
// Wstk rows 0-511=Wq, 512-1023=Wk, 1024-1535=Wv (contiguous in wt buffer).
// z = tn>>2: 0=Q (dual+phi), 1=K (dual+phi), 2=V (single, no phi).
// m97 pattern: global_load_lds w16 staging, BK=64, 4 waves in 2x2, 4x4 accs.
struct Qkv2Args {
    const bf16* xhi; const bf16* xlo; const bf16* wstk;
    const float* table;
    bf16* phiqB; bf16* phikB; float* phikF;
    float* vbufF; bf16* vbufT;
};

__global__ __launch_bounds__(256) void k_qkv2(Qkv2Args a) {
    __shared__ bf16 smem[3 * 128 * 64] __attribute__((aligned(16)));
    bf16* Ahi = smem;                 // [128][64]
    bf16* Bsm = smem + 8192;          // [128][64]
    bf16* Alo = smem + 16384;         // [128][64]
    __shared__ float tab[512];

    const int tid = threadIdx.x;
    const int wid = tid >> 6, lane = tid & 63;
    const int tm = blockIdx.x, tn = blockIdx.y;
    const int z = tn >> 2;
    const bool dual = (z < 2);

    if (z < 2) { tab[tid] = a.table[tid]; tab[tid + 256] = a.table[tid + 256]; }

    v4f acc[4][4];
    #pragma unroll
    for (int u = 0; u < 4; ++u)
        #pragma unroll
        for (int v = 0; v < 4; ++v) acc[u][v] = (v4f){0.f, 0.f, 0.f, 0.f};

    const char* Abh = (const char*)(a.xhi + (size_t)(tm * 128) * 512);
    const char* Abl = (const char*)(a.xlo + (size_t)(tm * 128) * 512);
    const char* Bb  = (const char*)(a.wstk + (size_t)(tn * 128) * 512);
    const int wm = wid >> 1, wn = wid & 1;
    const int q = lane >> 4, r = lane & 15;

    for (int k0 = 0; k0 < 512; k0 += 64) {
        // stage: instruction (j,wid) fills LDS bytes [(j*4+wid)*1024, +1024)
        // lane l covers tile row rbase+(l>>3), col bytes (l&7)*16
        #pragma unroll
        for (int j = 0; j < 4; ++j) {
            const int seg = j * 4 + wid;
            const int row = seg * 8 + (lane >> 3);
            const size_t goff = (size_t)row * 1024 + (size_t)k0 * 2 + (lane & 7) * 16;
            lds16(Abh + goff, (char*)Ahi + (seg << 10));
            lds16(Bb + goff, (char*)Bsm + (seg << 10));
            if (dual) lds16(Abl + goff, (char*)Alo + (seg << 10));
        }
        __syncthreads();
        #pragma unroll
        for (int s = 0; s < 2; ++s) {
            v8bf ah[4], bb[4];
            #pragma unroll
            for (int u = 0; u < 4; ++u)
                ah[u] = *(const v8bf*)&Ahi[(wm * 64 + u * 16 + r) * 64 + s * 32 + q * 8];
            #pragma unroll
            for (int v = 0; v < 4; ++v)
                bb[v] = *(const v8bf*)&Bsm[(wn * 64 + v * 16 + r) * 64 + s * 32 + q * 8];
            #pragma unroll
            for (int u = 0; u < 4; ++u)
                #pragma unroll
                for (int v = 0; v < 4; ++v)
                    acc[u][v] = __builtin_amdgcn_mfma_f32_16x16x32_bf16(ah[u], bb[v], acc[u][v], 0, 0, 0);
            if (dual) {
                v8bf al[4];
                #pragma unroll
                for (int u = 0; u < 4; ++u)
                    al[u] = *(const v8bf*)&Alo[(wm * 64 + u * 16 + r) * 64 + s * 32 + q * 8];
                #pragma unroll
                for (int u = 0; u < 4; ++u)
                    #pragma unroll
                    for (int v = 0; v < 4; ++v)
                        acc[u][v] = __builtin_amdgcn_mfma_f32_16x16x32_bf16(al[u], bb[v], acc[u][v], 0, 0, 0);
            }
        }
        __syncthreads();
    }

    // epilogue
    #pragma unroll
    for (int u = 0; u < 4; ++u) {
        const int mb = tm * 128 + wm * 64 + u * 16 + q * 4;
        const int b = mb >> 10, tpos = mb & 1023;
        #pragma unroll
        for (int v = 0; v < 4; ++v) {
            const int n = tn * 128 + wn * 64 + v * 16 + r;
            const int h = (n >> 6) & 7, d = n & 63;
            const int bh = b * 8 + h;
            float vals[4];
            #pragma unroll
            for (int i = 0; i < 4; ++i) {
                float val = acc[u][v][i];
                if (z < 2) {
                    int i0 = (int)rintf(val / 0.1f) + 128;
                    i0 = min(255, max(0, i0));
                    int i1 = (int)rintf(val / 0.2f) + 128;
                    i1 = min(255, max(0, i1));
                    val = tab[i0] + tab[256 + i1];
                }
                vals[i] = val;
            }
            if (z == 0) {
                #pragma unroll
                for (int i = 0; i < 4; ++i)
                    a.phiqB[((size_t)bh * 1024 + tpos + i) * 64 + d] = (bf16)vals[i];
            } else if (z == 1) {
                #pragma unroll
                for (int i = 0; i < 4; ++i) {
                    const size_t idx = ((size_t)bh * 1024 + tpos + i) * 64 + d;
                    a.phikB[idx] = (bf16)vals[i];
                    a.phikF[idx] = vals[i];
                }
            } else {
                #pragma unroll
                for (int i = 0; i < 4; ++i)
                    a.vbufF[((size_t)bh * 1024 + tpos + i) * 64 + d] = vals[i];
                union { uint2 pu; bf16 h4[4]; } P;
                #pragma unroll
                for (int i = 0; i < 4; ++i) P.h4[i] = (bf16)vals[i];
                *(uint2*)&a.vbufT[((size_t)bh * 64 + d) * 1024 + tpos] = P.pu;
            }
        }
    }
}

// ------------------------------------------------- per-chunk kv/k sums
// kvT output TRANSPOSED: kvT[bh][c][e*64+d]
__global__ __launch_bounds__(256) void k_chunksum(
        const float* __restrict__ phikF, const float* __restrict__ vbufF,
        float* __restrict__ kvT, float* __restrict__ ks) {
    const int c = blockIdx.x, bh = blockIdx.y;
    __shared__ float pk[32][64] __attribute__((aligned(16)));
    __shared__ float vv[32][64] __attribute__((aligned(16)));
    const int tid = threadIdx.x;
    const int e = tid & 63, g = tid >> 6;
    float kv[16];
    #pragma unroll
    for (int i = 0; i < 16; ++i) kv[i] = 0.f;
    const int srow = tid >> 3, scol = (tid & 7) * 8;
    const size_t base = (size_t)bh * 1024 + c * 128;

    for (int sub = 0; sub < 4; ++sub) {
        __syncthreads();
        const float* pg = phikF + (base + sub * 32 + srow) * 64 + scol;
        const float* vg = vbufF + (base + sub * 32 + srow) * 64 + scol;
        *(float4*)&pk[srow][scol]     = *(const float4*)pg;
        *(float4*)&pk[srow][scol + 4] = *(const float4*)(pg + 4);
        *(float4*)&vv[srow][scol]     = *(const float4*)vg;
        *(float4*)&vv[srow][scol + 4] = *(const float4*)(vg + 4);
        __syncthreads();
        for (int n = 0; n < 32; ++n) {
            const float vval = vv[n][e];
            const float4* prow = (const float4*)&pk[n][g * 16];
            float4 p0 = prow[0], p1 = prow[1], p2 = prow[2], p3 = prow[3];
            kv[0]  += p0.x * vval; kv[1]  += p0.y * vval; kv[2]  += p0.z * vval; kv[3]  += p0.w * vval;
            kv[4]  += p1.x * vval; kv[5]  += p1.y * vval; kv[6]  += p1.z * vval; kv[7]  += p1.w * vval;
            kv[8]  += p2.x * vval; kv[9]  += p2.y * vval; kv[10] += p2.z * vval; kv[11] += p2.w * vval;
            kv[12] += p3.x * vval; kv[13] += p3.y * vval; kv[14] += p3.z * vval; kv[15] += p3.w * vval;
        }
    }
    const size_t ob = ((size_t)bh * 8 + c) * 4096;
    #pragma unroll
    for (int w = 0; w < 4; ++w) {
        float4 s4 = {kv[4 * w], kv[4 * w + 1], kv[4 * w + 2], kv[4 * w + 3]};
        *(float4*)&kvT[ob + e * 64 + g * 16 + 4 * w] = s4;   // transposed [e][d]
    }
    if (tid < 64) {
        float s = 0.f;
        for (int n = 0; n < 128; ++n) s += phikF[(base + n) * 64 + tid];
        ks[((size_t)bh * 8 + c) * 64 + tid] = s;
    }
}

// ------------------------------------------------- exclusive chunk prefix
// writes bf16 exclusive prefix kvsB; ks prefixed in place (f32)
__global__ __launch_bounds__(256) void k_prefix(const float* __restrict__ kvT,
                                                bf16* __restrict__ kvsB,
                                                float* __restrict__ ks) {
    const int bh = blockIdx.x;
    const int p = blockIdx.y * 256 + threadIdx.x;
    float run = 0.f;
    #pragma unroll
    for (int c = 0; c < 8; ++c) {
        const size_t off = ((size_t)bh * 8 + c) * 4096 + p;
        kvsB[off] = (bf16)run;
        run += kvT[off];
    }
    if (blockIdx.y == 0 && threadIdx.x < 64) {
        const int tid = threadIdx.x;
        float runk = 0.f;
        #pragma unroll
        for (int c = 0; c < 8; ++c) {
            float* ptr = ks + ((size_t)bh * 8 + c) * 64 + tid;
            float v = *ptr; *ptr = runk; runk += v;
        }
    }
}

// ------------------------------------------------- intra-chunk attention (MFMA)
__global__ __launch_bounds__(256) void k_attn(
        const bf16* __restrict__ phiqB, const bf16* __restrict__ phikB,
        const bf16* __restrict__ vbufT, const bf16* __restrict__ kvsB,
        const float* __restrict__ ks, bf16* __restrict__ attn) {
    const int ntile = blockIdx.x, c = blockIdx.y, bh = blockIdx.z;
    __shared__ char smem[56064] __attribute__((aligned(16)));
    bf16* pqs  = (bf16*)smem;               // [64][72]
    bf16* kv0s = (bf16*)(smem + 9216);      // [64][72]
    bf16* Pbs  = (bf16*)smem;               // [64][136] overlay
    bf16* pks  = (bf16*)(smem + 18432);     // [128][72]
    bf16* vts  = (bf16*)(smem + 36864);     // [64][136]
    float* kc0s = (float*)(smem + 54272);   // [64]
    float* Zrow = (float*)(smem + 54528);   // [64]
    float* Zp   = (float*)(smem + 54784);   // [4][64]
    float* Zs   = (float*)(smem + 55808);   // [64]

    const int tid = threadIdx.x;
    const int wid = tid >> 6, lane = tid & 63;
    const int q = lane >> 4, r = lane & 15;
    const size_t tbase = (size_t)bh * 1024 + c * 128;
    const int t0 = ntile * 64;

    #pragma unroll
    for (int k = 0; k < 2; ++k) {
        const int idx = k * 256 + tid;
        const int row = idx >> 3, col = (idx & 7) * 8;
        *(uint4*)&pqs[row * 72 + col] =
            *(const uint4*)&phiqB[(tbase + t0 + row) * 64 + col];
        *(uint4*)&kv0s[row * 72 + col] =
            *(const uint4*)&kvsB[(((size_t)bh * 8 + c) * 64 + row) * 64 + col];
    }
    #pragma unroll
    for (int k = 0; k < 4; ++k) {
        const int idx = k * 256 + tid;
        const int row = idx >> 3, col = (idx & 7) * 8;
        *(uint4*)&pks[row * 72 + col] =
            *(const uint4*)&phikB[(tbase + row) * 64 + col];
        const int row2 = idx >> 4, col2 = (idx & 15) * 8;
        *(uint4*)&vts[row2 * 136 + col2] =
            *(const uint4*)&vbufT[((size_t)bh * 64 + row2) * 1024 + c * 128 + col2];
    }
    if (tid < 64) kc0s[tid] = ks[((size_t)bh * 8 + c) * 64 + tid];
    __syncthreads();

    v4f oacc[4], sacc[8];
    #pragma unroll
    for (int t = 0; t < 4; ++t) oacc[t] = (v4f){0.f, 0.f, 0.f, 0.f};
    #pragma unroll
    for (int u = 0; u < 8; ++u) sacc[u] = (v4f){0.f, 0.f, 0.f, 0.f};
    const int nmt = (ntile == 0) ? 4 : 8;

    #pragma unroll
    for (int kk = 0; kk < 2; ++kk) {
        v8bf af = *(const v8bf*)&pqs[(wid * 16 + r) * 72 + kk * 32 + q * 8];
        #pragma unroll
        for (int t = 0; t < 4; ++t) {
            v8bf bfr = *(const v8bf*)&kv0s[(t * 16 + r) * 72 + kk * 32 + q * 8];
            oacc[t] = __builtin_amdgcn_mfma_f32_16x16x32_bf16(af, bfr, oacc[t], 0, 0, 0);
        }
        #pragma unroll
        for (int u = 0; u < 8; ++u) {
            if (u < nmt) {
                v8bf bk = *(const v8bf*)&pks[(u * 16 + r) * 72 + kk * 32 + q * 8];
                sacc[u] = __builtin_amdgcn_mfma_f32_16x16x32_bf16(af, bk, sacc[u], 0, 0, 0);
            }
        }
    }
    {
        float z0 = 0.f;
        #pragma unroll
        for (int j = 0; j < 16; ++j)
            z0 += (float)pqs[lane * 72 + wid * 16 + j] * kc0s[wid * 16 + j];
        Zp[wid * 64 + lane] = z0;
    }
    __syncthreads();

    float zi[4] = {0.f, 0.f, 0.f, 0.f};
    #pragma unroll
    for (int u = 0; u < 8; ++u) {
        if (u < nmt) {
            const int m = u * 16 + r;
            #pragma unroll
            for (int i = 0; i < 4; ++i) {
                const int nloc = t0 + wid * 16 + q * 4 + i;
                const float sv = (m <= nloc) ? sacc[u][i] : 0.f;
                zi[i] += sv;
                Pbs[(wid * 16 + q * 4 + i) * 136 + m] = (bf16)sv;
            }
        }
    }
    #pragma unroll
    for (int w = 1; w < 16; w <<= 1) {
        #pragma unroll
        for (int i = 0; i < 4; ++i) zi[i] += __shfl_xor(zi[i], w);
    }
    if (r == 0) {
        #pragma unroll
        for (int i = 0; i < 4; ++i) Zrow[wid * 16 + q * 4 + i] = zi[i];
    }
    __syncthreads();

    if (tid < 64)
        Zs[tid] = fmaxf(Zrow[tid] + Zp[tid] + Zp[64 + tid] + Zp[128 + tid] + Zp[192 + tid],
                        1e-6f);
    __syncthreads();

    const int nkk = (ntile == 0) ? 2 : 4;
    #pragma unroll
    for (int kk = 0; kk < 4; ++kk) {
        if (kk < nkk) {
            v8bf af = *(const v8bf*)&Pbs[(wid * 16 + r) * 136 + kk * 32 + q * 8];
            #pragma unroll
            for (int t = 0; t < 4; ++t) {
                v8bf bfr = *(const v8bf*)&vts[(t * 16 + r) * 136 + kk * 32 + q * 8];
                oacc[t] = __builtin_amdgcn_mfma_f32_16x16x32_bf16(af, bfr, oacc[t], 0, 0, 0);
            }
        }
    }

    const int b = bh >> 3, h = bh & 7;
    #pragma unroll
    for (int t = 0; t < 4; ++t) {
        const int e = t * 16 + r;
        #pragma unroll
        for (int i = 0; i < 4; ++i) {
            const int row = wid * 16 + q * 4 + i;
            const float val = oacc[t][i] / Zs[row];
            const size_t mtok = (size_t)b * 1024 + c * 128 + t0 + row;
            attn[mtok * 512 + h * 64 + e] = (bf16)val;
        }
    }
}

// ------------------------------------------------- output projection (f32 out)
__device__ __forceinline__ void gemm_tile_64x64(
        const bf16* __restrict__ A, const bf16* __restrict__ Bm,
        int tm, int tn, bf16* As, bf16* Bs, v4f acc[4]) {
    const int tid = threadIdx.x;
    const int wid = tid >> 6, lane = tid & 63;
    const int q = lane >> 4, r = lane & 15;
    const int srow = tid >> 2;
    const int scol = (tid & 3) * 8;
    const bf16* Ag = A + ((size_t)(tm * 64 + srow)) * 512 + scol;
    const bf16* Bg = Bm + ((size_t)(tn * 64 + srow)) * 512 + scol;
    bf16* Asw = As + srow * 32 + scol;
    bf16* Bsw = Bs + srow * 32 + scol;
    for (int kk = 0; kk < 16; ++kk) {
        *(uint4*)Asw = *(const uint4*)(Ag + kk * 32);
        *(uint4*)Bsw = *(const uint4*)(Bg + kk * 32);
        __syncthreads();
        v8bf af = *(const v8bf*)(As + (wid * 16 + r) * 32 + q * 8);
        #pragma unroll
        for (int t = 0; t < 4; ++t) {
            v8bf bfr = *(const v8bf*)(Bs + (t * 16 + r) * 32 + q * 8);
            acc[t] = __builtin_amdgcn_mfma_f32_16x16x32_bf16(af, bfr, acc[t], 0, 0, 0);
        }
        __syncthreads();
    }
}

struct OArgs { const bf16* attn; const bf16* wo; const float* bo; float* y; };

__global__ __launch_bounds__(256) void k_oproj(OArgs a) {
    __shared__ bf16 As[64 * 32] __attribute__((aligned(16)));
    __shared__ bf16 Bs[64 * 32] __attribute__((aligned(16)));
    v4f acc[4];
    #pragma unroll
    for (int t = 0; t < 4; ++t) acc[t] = (v4f){0.f, 0.f, 0.f, 0.f};
    gemm_tile_64x64(a.attn, a.wo, blockIdx.x, blockIdx.y, As, Bs, acc);
    const int tid = threadIdx.x;
    const int wid = tid >> 6, lane = tid & 63;
    const int q = lane >> 4, r = lane & 15;
    #pragma unroll
    for (int t = 0; t < 4; ++t) {
        const int n = blockIdx.y * 64 + t * 16 + r;
        const float bias = a.bo[n];
        #pragma unroll
        for (int i = 0; i < 4; ++i) {
            const int m = blockIdx.x * 64 + wid * 16 + q * 4 + i;
            a.y[(size_t)m * 512 + n] = acc[t][i] + bias;
        }
    }
}

// ---------------------------------------------------------------- launch
extern "C" void kernel_launch(void* const* d_in, const int* in_sizes, int n_in,
                              void* d_out, int out_size, void* d_ws, size_t ws_size,
                              hipStream_t stream) {
    const float* x   = (const float*)d_in[0];
    const float* Wq  = (const float*)d_in[1];
    const float* Wk  = (const float*)d_in[2];
    const float* Wv  = (const float*)d_in[3];
    const float* Wo  = (const float*)d_in[4];
    const float* bo  = (const float*)d_in[5];
    const float* tab = (const float*)d_in[6];

    uint8_t* w = (uint8_t*)d_ws;
    bf16* wt     = (bf16*)w;                                  // 2 MB  [Wq;Wk;Wv;Wo] rows
    bf16* xhi    = wt + 4 * WN;                               // 2 MB
    bf16* xlo    = xhi + 1048576;                             // 2 MB
    float* phikF = (float*)(xlo + 1048576);                   // 4 MB
    float* vbufF = phikF + (size_t)16 * 1024 * 64;            // 4 MB
    float* kvT   = vbufF + (size_t)16 * 1024 * 64;            // 2 MB
    float* ks    = kvT + (size_t)16 * 8 * 4096;               // 32 KB
    bf16* attn   = (bf16*)(ks + 16 * 8 * 64);                 // 2 MB
    bf16* phiqB  = attn + (size_t)2048 * 512;                 // 2 MB
    bf16* phikB  = phiqB + (size_t)16 * 1024 * 64;            // 2 MB
    bf16* vbufT  = phikB + (size_t)16 * 1024 * 64;            // 2 MB
    bf16* kvsB   = vbufT + (size_t)16 * 64 * 1024;            // 1 MB
    float* partial = (float*)(kvsB + (size_t)16 * 8 * 4096);  // 256 f32

    AlphaArgs aa;
    aa.w[0] = Wq; aa.w[1] = Wk; aa.w[2] = Wv; aa.w[3] = Wo;
    aa.partial = partial;
    k_alpha<<<dim3(64, 4), dim3(256), 0, stream>>>(aa);

    WqArgs qa;
    qa.w[0] = Wq; qa.w[1] = Wk; qa.w[2] = Wv; qa.w[3] = Wo;
    qa.wt[0] = wt; qa.wt[1] = wt + WN; qa.wt[2] = wt + 2 * WN; qa.wt[3] = wt + 3 * WN;
    qa.partial = partial;
    k_wquant<<<dim3(64, 4), dim3(256), 0, stream>>>(qa);

    k_xsplit<<<dim3(1024), dim3(256), 0, stream>>>(x, xhi, xlo);

    Qkv2Args pa{ xhi, xlo, wt, tab, phiqB, phikB, phikF, vbufF, vbufT };
    k_qkv2<<<dim3(16, 12), dim3(256), 0, stream>>>(pa);

    k_chunksum<<<dim3(NCHUNK, BH), dim3(256), 0, stream>>>(phikF, vbufF, kvT, ks);
    k_prefix<<<dim3(16, 16), dim3(256), 0, stream>>>(kvT, kvsB, ks);
    k_attn<<<dim3(2, NCHUNK, BH), dim3(256), 0, stream>>>(phiqB, phikB, vbufT, kvsB, ks, attn);

    OArgs oa{ attn, wt + 3 * WN, bo, (float*)d_out };
    k_oproj<<<dim3(32, 8), dim3(256), 0, stream>>>(oa);
}

// Round 6
// 117.539 us; speedup vs baseline: 1.5349x; 1.1197x over previous
//
#include <hip/hip_runtime.h>
#include <stdint.h>

typedef __bf16 bf16;
typedef __bf16 v8bf __attribute__((ext_vector_type(8)));
typedef float v4f __attribute__((ext_vector_type(4)));

#define T_SEQ   1024
#define D_MODEL 512
#define N_HEADS 8
#define D_HEAD  64
#define B_SZ    2
#define BH      (B_SZ * N_HEADS)     // 16
#define CHUNK   128
#define NCHUNK  (T_SEQ / CHUNK)      // 8
#define WN      (D_MODEL * D_MODEL)  // 262144

// async global->LDS, 16B per lane; LDS dest is wave-uniform base + lane*16
__device__ __forceinline__ void lds16(const void* g, void* l) {
    __builtin_amdgcn_global_load_lds(
        (const __attribute__((address_space(1))) uint32_t*)g,
        (__attribute__((address_space(3))) uint32_t*)l, 16, 0, 0);
}

// ------------------------------------------------- weight quantize (2 stages)
struct AlphaArgs { const float* w[4]; float* partial; };

__global__ __launch_bounds__(256) void k_alpha(AlphaArgs a) {
    const int mid = blockIdx.y, blk = blockIdx.x, tid = threadIdx.x;
    const float* __restrict__ W = a.w[mid];
    float sabs = 0.f;
    #pragma unroll
    for (int k = 0; k < 4; ++k) {
        float4 v = ((const float4*)W)[blk * 1024 + k * 256 + tid];
        sabs += fabsf(v.x) + fabsf(v.y) + fabsf(v.z) + fabsf(v.w);
    }
    __shared__ float red[256];
    red[tid] = sabs;
    __syncthreads();
    for (int s = 128; s > 0; s >>= 1) {
        if (tid < s) red[tid] += red[tid + s];
        __syncthreads();
    }
    if (tid == 0) a.partial[mid * 64 + blk] = red[0];
}

struct WqArgs { const float* w[4]; bf16* wt[4]; const float* partial; };

__global__ __launch_bounds__(256) void k_wquant(WqArgs a) {
    const int mid = blockIdx.y, blk = blockIdx.x, tid = threadIdx.x;
    const float* __restrict__ W = a.w[mid];
    bf16* __restrict__ Wt = a.wt[mid];
    __shared__ float sv;
    if (tid < 64) {
        float p = a.partial[mid * 64 + tid];
        #pragma unroll
        for (int w = 1; w < 64; w <<= 1) p += __shfl_xor(p, w);
        if (tid == 0) {
            float alpha = p / (float)WN + 1e-12f;
            float e = rintf(log2f(alpha));
            e = fminf(4.f, fmaxf(-4.f, e));
            sv = exp2f(e);
        }
    }
    __syncthreads();
    const float s = sv;
    const float inv_s = 1.f / s;              // s is a power of two: exact
    #pragma unroll
    for (int k = 0; k < 4; ++k) {
        const int idx = blk * 1024 + k * 256 + tid;
        float4 v = ((const float4*)W)[idx];
        float vv[4] = {v.x, v.y, v.z, v.w};
        union { uint2 u; bf16 h[4]; } o;
        #pragma unroll
        for (int j = 0; j < 4; ++j) {
            float r = rintf(vv[j] * inv_s);
            r = fminf(1.f, fmaxf(-1.f, r));
            o.h[j] = (bf16)(r * s);
        }
        ((uint2*)Wt)[idx] = o.u;
    }
}

// ------------------------------------------------- x -> bf16 hi/lo split
__global__ __launch_bounds__(256) void k_xsplit(const float* __restrict__ x,
                                                bf16* __restrict__ xhi,
                                                bf16* __restrict__ xlo) {
    const int i = blockIdx.x * 256 + threadIdx.x;   // float4 index
    float4 v = ((const float4*)x)[i];
    float vv[4] = {v.x, v.y, v.z, v.w};
    union { uint2 u; bf16 h[4]; } H, L;
    #pragma unroll
    for (int j = 0; j < 4; ++j) {
        bf16 hb = (bf16)vv[j];
        H.h[j] = hb;
        L.h[j] = (bf16)(vv[j] - (float)hb);
    }
    ((uint2*)xhi)[i] = H.u;
    ((uint2*)xlo)[i] = L.u;
}

// ------------------------------------------------- 64x64 swizzled GEMM core
// C(64x64) = A[64][512] @ B[64][512]^T (NT), K=512, BK=64, global_load_lds w16.
// LDS layout XOR-swizzled: phys[row][c] = logical[row][c ^ (row&7)], c = 16B chunk.
// Swizzle applied on the GLOBAL SOURCE address (dest must stay base+lane*16);
// fragment reads then cover all 32 banks (2-way only, free).
// wave wm computes rows wm*16..+15, acc[v] covers cols v*16..+15.
template <bool DUAL>
__device__ __forceinline__ void gemm64(
        const char* __restrict__ Ah, const char* __restrict__ Al,
        const char* __restrict__ Bb,
        bf16* Ahi, bf16* Alo, bf16* Bsm, v4f acc[4]) {
    const int tid = threadIdx.x;
    const int wm = tid >> 6, lane = tid & 63;
    const int q = lane >> 4, r = lane & 15;
    const int lrow = lane >> 3;               // 0..7
    const int schunk = (lane & 7) ^ lrow;     // swizzled source chunk
    const int r7 = r & 7;

    for (int k0 = 0; k0 < 512; k0 += 64) {
        #pragma unroll
        for (int j = 0; j < 2; ++j) {
            const int seg = wm * 2 + j;       // 8 segs over 4 waves
            const int row = seg * 8 + lrow;
            const size_t goff = (size_t)row * 1024 + (size_t)k0 * 2 + schunk * 16;
            lds16(Ah + goff, (char*)Ahi + (seg << 10));
            lds16(Bb + goff, (char*)Bsm + (seg << 10));
            if (DUAL) lds16(Al + goff, (char*)Alo + (seg << 10));
        }
        __syncthreads();
        #pragma unroll
        for (int s = 0; s < 2; ++s) {
            const int co = ((s * 4 + q) ^ r7) * 8;     // swizzled read chunk
            v8bf ah = *(const v8bf*)&Ahi[(wm * 16 + r) * 64 + co];
            v8bf bb[4];
            #pragma unroll
            for (int v = 0; v < 4; ++v)
                bb[v] = *(const v8bf*)&Bsm[(v * 16 + r) * 64 + co];
            #pragma unroll
            for (int v = 0; v < 4; ++v)
                acc[v] = __builtin_amdgcn_mfma_f32_16x16x32_bf16(ah, bb[v], acc[v], 0, 0, 0);
            if (DUAL) {
                v8bf al = *(const v8bf*)&Alo[(wm * 16 + r) * 64 + co];
                #pragma unroll
                for (int v = 0; v < 4; ++v)
                    acc[v] = __builtin_amdgcn_mfma_f32_16x16x32_bf16(al, bb[v], acc[v], 0, 0, 0);
            }
        }
        __syncthreads();
    }
}

// ------------------------------------------------- fused QKV GEMM (+phi)
// Wstk rows: 0-511=Wq, 512-1023=Wk, 1024-1535=Wv. tn in 0..23, z = tn>>3.
struct Qkv2Args {
    const bf16* xhi; const bf16* xlo; const bf16* wstk;
    const float* table;
    bf16* phiqB; bf16* phikB; float* phikF;
    float* vbufF; bf16* vbufT;
};

__global__ __launch_bounds__(256) void k_qkv2(Qkv2Args a) {
    __shared__ bf16 Ahi[64 * 64] __attribute__((aligned(16)));
    __shared__ bf16 Alo[64 * 64] __attribute__((aligned(16)));
    __shared__ bf16 Bsm[64 * 64] __attribute__((aligned(16)));
    __shared__ float tab[512];
    const int tid = threadIdx.x;
    const int tm = blockIdx.x, tn = blockIdx.y;
    const int z = tn >> 3;
    if (z < 2) { tab[tid] = a.table[tid]; tab[tid + 256] = a.table[tid + 256]; }

    v4f acc[4];
    #pragma unroll
    for (int v = 0; v < 4; ++v) acc[v] = (v4f){0.f, 0.f, 0.f, 0.f};

    const char* Ah = (const char*)(a.xhi + (size_t)(tm * 64) * 512);
    const char* Al = (const char*)(a.xlo + (size_t)(tm * 64) * 512);
    const char* Bb = (const char*)(a.wstk + (size_t)(tn * 64) * 512);
    if (z < 2) gemm64<true >(Ah, Al, Bb, Ahi, Alo, Bsm, acc);
    else       gemm64<false>(Ah, Al, Bb, Ahi, Alo, Bsm, acc);

    // epilogue
    const int wm = tid >> 6, lane = tid & 63;
    const int q = lane >> 4, r = lane & 15;
    const int mb = tm * 64 + wm * 16 + q * 4;     // token row base (4 consecutive)
    const int b = mb >> 10, tpos = mb & 1023;
    #pragma unroll
    for (int v = 0; v < 4; ++v) {
        const int n = tn * 64 + v * 16 + r;
        const int h = (n >> 6) & 7, d = n & 63;
        const int bh = b * 8 + h;
        float vals[4];
        #pragma unroll
        for (int i = 0; i < 4; ++i) {
            float val = acc[v][i];
            if (z < 2) {
                int i0 = (int)rintf(val / 0.1f) + 128;
                i0 = min(255, max(0, i0));
                int i1 = (int)rintf(val / 0.2f) + 128;
                i1 = min(255, max(0, i1));
                val = tab[i0] + tab[256 + i1];
            }
            vals[i] = val;
        }
        if (z == 0) {
            #pragma unroll
            for (int i = 0; i < 4; ++i)
                a.phiqB[((size_t)bh * 1024 + tpos + i) * 64 + d] = (bf16)vals[i];
        } else if (z == 1) {
            #pragma unroll
            for (int i = 0; i < 4; ++i) {
                const size_t idx = ((size_t)bh * 1024 + tpos + i) * 64 + d;
                a.phikB[idx] = (bf16)vals[i];
                a.phikF[idx] = vals[i];
            }
        } else {
            #pragma unroll
            for (int i = 0; i < 4; ++i)
                a.vbufF[((size_t)bh * 1024 + tpos + i) * 64 + d] = vals[i];
            union { uint2 pu; bf16 h4[4]; } P;
            #pragma unroll
            for (int i = 0; i < 4; ++i) P.h4[i] = (bf16)vals[i];
            *(uint2*)&a.vbufT[((size_t)bh * 64 + d) * 1024 + tpos] = P.pu;
        }
    }
}

// ------------------------------------------------- per-chunk kv/k sums
// kvT output TRANSPOSED: kvT[bh][c][e*64+d]
__global__ __launch_bounds__(256) void k_chunksum(
        const float* __restrict__ phikF, const float* __restrict__ vbufF,
        float* __restrict__ kvT, float* __restrict__ ks) {
    const int c = blockIdx.x, bh = blockIdx.y;
    __shared__ float pk[32][64] __attribute__((aligned(16)));
    __shared__ float vv[32][64] __attribute__((aligned(16)));
    const int tid = threadIdx.x;
    const int e = tid & 63, g = tid >> 6;
    float kv[16];
    #pragma unroll
    for (int i = 0; i < 16; ++i) kv[i] = 0.f;
    const int srow = tid >> 3, scol = (tid & 7) * 8;
    const size_t base = (size_t)bh * 1024 + c * 128;

    for (int sub = 0; sub < 4; ++sub) {
        __syncthreads();
        const float* pg = phikF + (base + sub * 32 + srow) * 64 + scol;
        const float* vg = vbufF + (base + sub * 32 + srow) * 64 + scol;
        *(float4*)&pk[srow][scol]     = *(const float4*)pg;
        *(float4*)&pk[srow][scol + 4] = *(const float4*)(pg + 4);
        *(float4*)&vv[srow][scol]     = *(const float4*)vg;
        *(float4*)&vv[srow][scol + 4] = *(const float4*)(vg + 4);
        __syncthreads();
        for (int n = 0; n < 32; ++n) {
            const float vval = vv[n][e];
            const float4* prow = (const float4*)&pk[n][g * 16];
            float4 p0 = prow[0], p1 = prow[1], p2 = prow[2], p3 = prow[3];
            kv[0]  += p0.x * vval; kv[1]  += p0.y * vval; kv[2]  += p0.z * vval; kv[3]  += p0.w * vval;
            kv[4]  += p1.x * vval; kv[5]  += p1.y * vval; kv[6]  += p1.z * vval; kv[7]  += p1.w * vval;
            kv[8]  += p2.x * vval; kv[9]  += p2.y * vval; kv[10] += p2.z * vval; kv[11] += p2.w * vval;
            kv[12] += p3.x * vval; kv[13] += p3.y * vval; kv[14] += p3.z * vval; kv[15] += p3.w * vval;
        }
    }
    const size_t ob = ((size_t)bh * 8 + c) * 4096;
    #pragma unroll
    for (int w = 0; w < 4; ++w) {
        float4 s4 = {kv[4 * w], kv[4 * w + 1], kv[4 * w + 2], kv[4 * w + 3]};
        *(float4*)&kvT[ob + e * 64 + g * 16 + 4 * w] = s4;   // transposed [e][d]
    }
    if (tid < 64) {
        float s = 0.f;
        for (int n = 0; n < 128; ++n) s += phikF[(base + n) * 64 + tid];
        ks[((size_t)bh * 8 + c) * 64 + tid] = s;
    }
}

// ------------------------------------------------- exclusive chunk prefix
__global__ __launch_bounds__(256) void k_prefix(const float* __restrict__ kvT,
                                                bf16* __restrict__ kvsB,
                                                float* __restrict__ ks) {
    const int bh = blockIdx.x;
    const int p = blockIdx.y * 256 + threadIdx.x;
    float run = 0.f;
    #pragma unroll
    for (int c = 0; c < 8; ++c) {
        const size_t off = ((size_t)bh * 8 + c) * 4096 + p;
        kvsB[off] = (bf16)run;
        run += kvT[off];
    }
    if (blockIdx.y == 0 && threadIdx.x < 64) {
        const int tid = threadIdx.x;
        float runk = 0.f;
        #pragma unroll
        for (int c = 0; c < 8; ++c) {
            float* ptr = ks + ((size_t)bh * 8 + c) * 64 + tid;
            float v = *ptr; *ptr = runk; runk += v;
        }
    }
}

// ------------------------------------------------- intra-chunk attention (MFMA)
__global__ __launch_bounds__(256) void k_attn(
        const bf16* __restrict__ phiqB, const bf16* __restrict__ phikB,
        const bf16* __restrict__ vbufT, const bf16* __restrict__ kvsB,
        const float* __restrict__ ks, bf16* __restrict__ attn) {
    const int ntile = blockIdx.x, c = blockIdx.y, bh = blockIdx.z;
    __shared__ char smem[56064] __attribute__((aligned(16)));
    bf16* pqs  = (bf16*)smem;               // [64][72]
    bf16* kv0s = (bf16*)(smem + 9216);      // [64][72]
    bf16* Pbs  = (bf16*)smem;               // [64][136] overlay
    bf16* pks  = (bf16*)(smem + 18432);     // [128][72]
    bf16* vts  = (bf16*)(smem + 36864);     // [64][136]
    float* kc0s = (float*)(smem + 54272);   // [64]
    float* Zrow = (float*)(smem + 54528);   // [64]
    float* Zp   = (float*)(smem + 54784);   // [4][64]
    float* Zs   = (float*)(smem + 55808);   // [64]

    const int tid = threadIdx.x;
    const int wid = tid >> 6, lane = tid & 63;
    const int q = lane >> 4, r = lane & 15;
    const size_t tbase = (size_t)bh * 1024 + c * 128;
    const int t0 = ntile * 64;

    #pragma unroll
    for (int k = 0; k < 2; ++k) {
        const int idx = k * 256 + tid;
        const int row = idx >> 3, col = (idx & 7) * 8;
        *(uint4*)&pqs[row * 72 + col] =
            *(const uint4*)&phiqB[(tbase + t0 + row) * 64 + col];
        *(uint4*)&kv0s[row * 72 + col] =
            *(const uint4*)&kvsB[(((size_t)bh * 8 + c) * 64 + row) * 64 + col];
    }
    #pragma unroll
    for (int k = 0; k < 4; ++k) {
        const int idx = k * 256 + tid;
        const int row = idx >> 3, col = (idx & 7) * 8;
        *(uint4*)&pks[row * 72 + col] =
            *(const uint4*)&phikB[(tbase + row) * 64 + col];
        const int row2 = idx >> 4, col2 = (idx & 15) * 8;
        *(uint4*)&vts[row2 * 136 + col2] =
            *(const uint4*)&vbufT[((size_t)bh * 64 + row2) * 1024 + c * 128 + col2];
    }
    if (tid < 64) kc0s[tid] = ks[((size_t)bh * 8 + c) * 64 + tid];
    __syncthreads();

    v4f oacc[4], sacc[8];
    #pragma unroll
    for (int t = 0; t < 4; ++t) oacc[t] = (v4f){0.f, 0.f, 0.f, 0.f};
    #pragma unroll
    for (int u = 0; u < 8; ++u) sacc[u] = (v4f){0.f, 0.f, 0.f, 0.f};
    const int nmt = (ntile == 0) ? 4 : 8;

    #pragma unroll
    for (int kk = 0; kk < 2; ++kk) {
        v8bf af = *(const v8bf*)&pqs[(wid * 16 + r) * 72 + kk * 32 + q * 8];
        #pragma unroll
        for (int t = 0; t < 4; ++t) {
            v8bf bfr = *(const v8bf*)&kv0s[(t * 16 + r) * 72 + kk * 32 + q * 8];
            oacc[t] = __builtin_amdgcn_mfma_f32_16x16x32_bf16(af, bfr, oacc[t], 0, 0, 0);
        }
        #pragma unroll
        for (int u = 0; u < 8; ++u) {
            if (u < nmt) {
                v8bf bk = *(const v8bf*)&pks[(u * 16 + r) * 72 + kk * 32 + q * 8];
                sacc[u] = __builtin_amdgcn_mfma_f32_16x16x32_bf16(af, bk, sacc[u], 0, 0, 0);
            }
        }
    }
    {
        float z0 = 0.f;
        #pragma unroll
        for (int j = 0; j < 16; ++j)
            z0 += (float)pqs[lane * 72 + wid * 16 + j] * kc0s[wid * 16 + j];
        Zp[wid * 64 + lane] = z0;
    }
    __syncthreads();

    float zi[4] = {0.f, 0.f, 0.f, 0.f};
    #pragma unroll
    for (int u = 0; u < 8; ++u) {
        if (u < nmt) {
            const int m = u * 16 + r;
            #pragma unroll
            for (int i = 0; i < 4; ++i) {
                const int nloc = t0 + wid * 16 + q * 4 + i;
                const float sv = (m <= nloc) ? sacc[u][i] : 0.f;
                zi[i] += sv;
                Pbs[(wid * 16 + q * 4 + i) * 136 + m] = (bf16)sv;
            }
        }
    }
    #pragma unroll
    for (int w = 1; w < 16; w <<= 1) {
        #pragma unroll
        for (int i = 0; i < 4; ++i) zi[i] += __shfl_xor(zi[i], w);
    }
    if (r == 0) {
        #pragma unroll
        for (int i = 0; i < 4; ++i) Zrow[wid * 16 + q * 4 + i] = zi[i];
    }
    __syncthreads();

    if (tid < 64)
        Zs[tid] = fmaxf(Zrow[tid] + Zp[tid] + Zp[64 + tid] + Zp[128 + tid] + Zp[192 + tid],
                        1e-6f);
    __syncthreads();

    const int nkk = (ntile == 0) ? 2 : 4;
    #pragma unroll
    for (int kk = 0; kk < 4; ++kk) {
        if (kk < nkk) {
            v8bf af = *(const v8bf*)&Pbs[(wid * 16 + r) * 136 + kk * 32 + q * 8];
            #pragma unroll
            for (int t = 0; t < 4; ++t) {
                v8bf bfr = *(const v8bf*)&vts[(t * 16 + r) * 136 + kk * 32 + q * 8];
                oacc[t] = __builtin_amdgcn_mfma_f32_16x16x32_bf16(af, bfr, oacc[t], 0, 0, 0);
            }
        }
    }

    const int b = bh >> 3, h = bh & 7;
    #pragma unroll
    for (int t = 0; t < 4; ++t) {
        const int e = t * 16 + r;
        #pragma unroll
        for (int i = 0; i < 4; ++i) {
            const int row = wid * 16 + q * 4 + i;
            const float val = oacc[t][i] / Zs[row];
            const size_t mtok = (size_t)b * 1024 + c * 128 + t0 + row;
            attn[mtok * 512 + h * 64 + e] = (bf16)val;
        }
    }
}

// ------------------------------------------------- output projection (f32 out)
struct OArgs { const bf16* attn; const bf16* wo; const float* bo; float* y; };

__global__ __launch_bounds__(256) void k_oproj(OArgs a) {
    __shared__ bf16 Ahi[64 * 64] __attribute__((aligned(16)));
    __shared__ bf16 Bsm[64 * 64] __attribute__((aligned(16)));
    v4f acc[4];
    #pragma unroll
    for (int v = 0; v < 4; ++v) acc[v] = (v4f){0.f, 0.f, 0.f, 0.f};
    const char* Ah = (const char*)(a.attn + (size_t)(blockIdx.x * 64) * 512);
    const char* Bb = (const char*)(a.wo + (size_t)(blockIdx.y * 64) * 512);
    gemm64<false>(Ah, nullptr, Bb, Ahi, nullptr, Bsm, acc);

    const int tid = threadIdx.x;
    const int wm = tid >> 6, lane = tid & 63;
    const int q = lane >> 4, r = lane & 15;
    #pragma unroll
    for (int v = 0; v < 4; ++v) {
        const int n = blockIdx.y * 64 + v * 16 + r;
        const float bias = a.bo[n];
        #pragma unroll
        for (int i = 0; i < 4; ++i) {
            const int m = blockIdx.x * 64 + wm * 16 + q * 4 + i;
            a.y[(size_t)m * 512 + n] = acc[v][i] + bias;
        }
    }
}

// ---------------------------------------------------------------- launch
extern "C" void kernel_launch(void* const* d_in, const int* in_sizes, int n_in,
                              void* d_out, int out_size, void* d_ws, size_t ws_size,
                              hipStream_t stream) {
    const float* x   = (const float*)d_in[0];
    const float* Wq  = (const float*)d_in[1];
    const float* Wk  = (const float*)d_in[2];
    const float* Wv  = (const float*)d_in[3];
    const float* Wo  = (const float*)d_in[4];
    const float* bo  = (const float*)d_in[5];
    const float* tab = (const float*)d_in[6];

    uint8_t* w = (uint8_t*)d_ws;
    bf16* wt     = (bf16*)w;                                  // 2 MB  [Wq;Wk;Wv;Wo]
    bf16* xhi    = wt + 4 * WN;                               // 2 MB
    bf16* xlo    = xhi + 1048576;                             // 2 MB
    float* phikF = (float*)(xlo + 1048576);                   // 4 MB
    float* vbufF = phikF + (size_t)16 * 1024 * 64;            // 4 MB
    float* kvT   = vbufF + (size_t)16 * 1024 * 64;            // 2 MB
    float* ks    = kvT + (size_t)16 * 8 * 4096;               // 32 KB
    bf16* attn   = (bf16*)(ks + 16 * 8 * 64);                 // 2 MB
    bf16* phiqB  = attn + (size_t)2048 * 512;                 // 2 MB
    bf16* phikB  = phiqB + (size_t)16 * 1024 * 64;            // 2 MB
    bf16* vbufT  = phikB + (size_t)16 * 1024 * 64;            // 2 MB
    bf16* kvsB   = vbufT + (size_t)16 * 64 * 1024;            // 1 MB
    float* partial = (float*)(kvsB + (size_t)16 * 8 * 4096);  // 256 f32

    AlphaArgs aa;
    aa.w[0] = Wq; aa.w[1] = Wk; aa.w[2] = Wv; aa.w[3] = Wo;
    aa.partial = partial;
    k_alpha<<<dim3(64, 4), dim3(256), 0, stream>>>(aa);

    WqArgs qa;
    qa.w[0] = Wq; qa.w[1] = Wk; qa.w[2] = Wv; qa.w[3] = Wo;
    qa.wt[0] = wt; qa.wt[1] = wt + WN; qa.wt[2] = wt + 2 * WN; qa.wt[3] = wt + 3 * WN;
    qa.partial = partial;
    k_wquant<<<dim3(64, 4), dim3(256), 0, stream>>>(qa);

    k_xsplit<<<dim3(1024), dim3(256), 0, stream>>>(x, xhi, xlo);

    Qkv2Args pa{ xhi, xlo, wt, tab, phiqB, phikB, phikF, vbufF, vbufT };
    k_qkv2<<<dim3(32, 24), dim3(256), 0, stream>>>(pa);

    k_chunksum<<<dim3(NCHUNK, BH), dim3(256), 0, stream>>>(phikF, vbufF, kvT, ks);
    k_prefix<<<dim3(16, 16), dim3(256), 0, stream>>>(kvT, kvsB, ks);
    k_attn<<<dim3(2, NCHUNK, BH), dim3(256), 0, stream>>>(phiqB, phikB, vbufT, kvsB, ks, attn);

    OArgs oa{ attn, wt + 3 * WN, bo, (float*)d_out };
    k_oproj<<<dim3(32, 8), dim3(256), 0, stream>>>(oa);
}